// Round 30
// baseline (831.226 us; speedup 1.0000x reference)
//
#include <hip/hip_runtime.h>
#include <math.h>

// ---- problem constants (B=256, C=3, H=64, D=256, E=16, Hg=64, R=32, L=2, hid=128) ----
#define OUT_ELBO  3145728
#define OUT_NACT  3145729
#define OUT_IMP   3145730
#define OUT_VINST 3145986

__device__ __forceinline__ float relu_(float v){ return fmaxf(v, 0.f); }

__device__ __forceinline__ unsigned short f2bf(float f){
  unsigned int u = __float_as_uint(f);
  unsigned int r = (u + 0x7FFFu + ((u>>16)&1u)) >> 16;
  return (unsigned short)r;
}

typedef __attribute__((ext_vector_type(8))) short short8;
typedef __attribute__((ext_vector_type(4))) float f32x4;

// ================= encoder conv1: (256,3,64,64) -> (256,64,32,32), k4 s2 p1, ReLU =================
__global__ __launch_bounds__(512) void k_conv1(const float* __restrict__ in,
    const float* __restrict__ w, const float* __restrict__ bias, float* __restrict__ out){
  __shared__ float li[13068];          // 3 * 66*66
  __shared__ float lw[1536];           // 48 taps * 32 co
  int cohalf = blockIdx.x & 1;
  int n      = blockIdx.x >> 1;
  int co0 = cohalf*32;
  int tid = threadIdx.x;
  for (int i=tid; i<13068; i+=512) li[i] = 0.f;
  __syncthreads();
  const float* ip = in + (size_t)n*12288;
  for (int i=tid; i<12288; i+=512){
    int ci = i >> 12, rem = i & 4095;
    int yy = rem >> 6, xx = rem & 63;
    li[ci*4356 + (yy+1)*66 + xx+1] = ip[i];
  }
  for (int i=tid; i<1536; i+=512){
    int t = i >> 5, c = i & 31;
    lw[i] = w[(co0+c)*48 + t];
  }
  __syncthreads();
  int x = tid & 31, y8 = tid >> 5;     // y8 in [0,16)
  #pragma unroll
  for (int cc=0; cc<4; cc++){
    float acc[2][8];
    #pragma unroll
    for (int q=0;q<2;q++)
      #pragma unroll
      for (int c=0;c<8;c++) acc[q][c]=0.f;
    #pragma unroll
    for (int ci=0; ci<3; ci++){
      int cb = ci*4356;
      #pragma unroll
      for (int ky=0; ky<4; ky++){
        float v[2][4];
        #pragma unroll
        for (int q=0;q<2;q++){
          int y = y8 + 16*q;
          int rb = cb + (2*y+ky)*66 + 2*x;
          v[q][0]=li[rb]; v[q][1]=li[rb+1]; v[q][2]=li[rb+2]; v[q][3]=li[rb+3];
        }
        float wv[4][8];
        #pragma unroll
        for (int kx=0;kx<4;kx++){
          int wb = ((ci*4+ky)*4+kx)*32 + cc*8;
          #pragma unroll
          for (int c=0;c<8;c++) wv[kx][c] = lw[wb+c];
        }
        #pragma unroll
        for (int q=0;q<2;q++)
          #pragma unroll
          for (int kx=0;kx<4;kx++)
            #pragma unroll
            for (int c=0;c<8;c++)
              acc[q][c] += v[q][kx]*wv[kx][c];
      }
    }
    #pragma unroll
    for (int c=0;c<8;c++){
      int co = co0 + cc*8 + c;
      float bv = bias[co];
      #pragma unroll
      for (int q=0;q<2;q++){
        int y = y8 + 16*q;
        out[(((size_t)n*64+co)*32 + y)*32 + x] = relu_(acc[q][c] + bv);
      }
    }
  }
}

// ================= conv2 weights: w[co][ci][t] f32 (128,64,16) -> Wt2[t][co][ci] bf16 ============
__global__ __launch_bounds__(256) void k_wt2(const float* __restrict__ w,
    unsigned short* __restrict__ Wt){
  int idx = blockIdx.x*256 + threadIdx.x;   // 131072 total
  int ci = idx & 63;
  int r = idx >> 6;          // t*128 + co
  int t = r >> 7, co = r & 127;
  Wt[idx] = f2bf(w[((co*64 + ci)<<4) + t]);
}

// ================= conv2 act transpose: in[n][64][1024] f32 -> At2[n][34*34][64] bf16 ===========
// grid 512 = 128 img x 4 px-chunks; 33.8 KB LDS, 4 blocks/CU.
__global__ __launch_bounds__(256) void k_at2(const float* __restrict__ in,
    unsigned short* __restrict__ At){
  __shared__ unsigned int l[256*33];     // 256 px x 32 words (64 ci), pad->33
  int b = blockIdx.x;
  int c = b & 3;
  int n = b >> 2;
  int tid = threadIdx.x;
  const float* ip = in + (size_t)n*65536;
  unsigned short* Ab = At + (size_t)n*1156*64;
  int pxg = c*256 + tid;
  for (int j=0;j<64;j+=2){
    float a = ip[j*1024 + pxg];
    float bb = ip[(j+1)*1024 + pxg];
    l[tid*33 + (j>>1)] = (unsigned int)f2bf(a) | ((unsigned int)f2bf(bb)<<16);
  }
  __syncthreads();
  #pragma unroll
  for (int it=0; it<8; it++){
    int u = it*256 + tid;
    int pxl = u >> 3, seg = u & 7;
    int pxg2 = c*256 + pxl;
    int y = pxg2 >> 5, x = pxg2 & 31;
    int pp = (y+1)*34 + (x+1);
    uint4 v;
    v.x = l[pxl*33 + seg*4 + 0];
    v.y = l[pxl*33 + seg*4 + 1];
    v.z = l[pxl*33 + seg*4 + 2];
    v.w = l[pxl*33 + seg*4 + 3];
    *(uint4*)(Ab + pp*64 + seg*8) = v;
  }
  // halo: 1056 units total, chunk c fills [c*264, c*264+264)
  uint4 z; z.x=0; z.y=0; z.z=0; z.w=0;
  for (int it=0; it<2; it++){
    int ul = it*256 + tid;
    if (ul >= 264) break;
    int u = c*264 + ul;
    int h = u >> 3, seg = u & 7;
    int pp;
    if (h < 34) pp = h;
    else if (h < 68) pp = 1122 + (h-34);
    else { int s = h-68; pp = (1 + (s>>1))*34 + (s&1)*33; }
    *(uint4*)(Ab + pp*64 + seg*8) = z;
  }
}

// ================= conv2 MFMA: out[n][128co][256px] = relu(At2 * Wt2 + b) =======================
__global__ __launch_bounds__(256) void k_c2mfma(const unsigned short* __restrict__ At,
    const unsigned short* __restrict__ Wt, const float* __restrict__ bias,
    float* __restrict__ out){
  int b = blockIdx.x;
  int wsw = (b & 7)*32 + (b >> 3);     // grid 256, 8 XCDs: image-halves co-located per XCD
  int half = wsw & 1;
  int n    = wsw >> 1;
  int tid = threadIdx.x;
  int wid = tid >> 6, lane = tid & 63;
  int wn = wid & 1, wm = wid >> 1;
  int lrow = lane & 15, lkb = lane >> 4;
  f32x4 acc[4][4];
  #pragma unroll
  for (int i=0;i<4;i++)
    #pragma unroll
    for (int j=0;j<4;j++){ acc[i][j].x=0.f; acc[i][j].y=0.f; acc[i][j].z=0.f; acc[i][j].w=0.f; }
  const unsigned short* Ab = At + (size_t)n*1156*64;
  int mbase = half*128 + wm*64;
  #pragma unroll
  for (int t=0; t<16; t++){
    int ky = t >> 2, kx = t & 3;
    #pragma unroll
    for (int kc=0; kc<2; kc++){
      int k0 = kc*32 + lkb*8;
      short8 a[4], b2[4];
      #pragma unroll
      for (int i=0;i<4;i++){
        int m = mbase + i*16 + lrow;
        int y = m >> 4, x = m & 15;
        int pp = (2*y+ky)*34 + (2*x+kx);
        a[i] = *(const short8*)(Ab + pp*64 + k0);
      }
      #pragma unroll
      for (int j=0;j<4;j++){
        int co = wn*64 + j*16 + lrow;
        b2[j] = *(const short8*)(Wt + (t*128 + co)*64 + k0);
      }
      #pragma unroll
      for (int i=0;i<4;i++)
        #pragma unroll
        for (int j=0;j<4;j++)
          acc[i][j] = __builtin_amdgcn_mfma_f32_16x16x32_bf16(a[i], b2[j], acc[i][j], 0,0,0);
    }
  }
  #pragma unroll
  for (int j=0;j<4;j++){
    int co = wn*64 + j*16 + lrow;
    float bv = bias[co];
    #pragma unroll
    for (int i=0;i<4;i++){
      int px0 = mbase + i*16 + lkb*4;
      f32x4 v = acc[i][j];
      v.x = relu_(v.x + bv); v.y = relu_(v.y + bv);
      v.z = relu_(v.z + bv); v.w = relu_(v.w + bv);
      *(f32x4*)(out + ((size_t)n*128+co)*256 + px0) = v;
    }
  }
}

// ================= conv3x3 weights: w[co][ci][t] f32 -> Wt[t][co][ci] bf16 ====================
__global__ __launch_bounds__(256) void k_wt(const float* __restrict__ w,
    unsigned short* __restrict__ Wt, int Co){
  int idx = blockIdx.x*256 + threadIdx.x;
  int tot = Co*128*9;
  if (idx >= tot) return;
  int ci = idx & 127;
  int r = idx >> 7;          // t*Co + co
  int t = r / Co, co = r - t*Co;
  Wt[idx] = f2bf(w[(co*128 + ci)*9 + t]);
}

// ================= deconv1 weights: w[ky][kx][ci][co] f32 (4,4,128,64) -> Wt1[t][co][ci] bf16 ====
__global__ __launch_bounds__(256) void k_wt1(const float* __restrict__ w,
    unsigned short* __restrict__ Wt){
  int idx = blockIdx.x*256 + threadIdx.x;   // 131072 total
  int ci = idx & 127;
  int r = idx >> 7;          // t*64 + co
  int t = r >> 6, co = r & 63;
  Wt[idx] = f2bf(w[t*8192 + ci*64 + co]);
}

// ================= conv3x3 act transpose: in[n][128][256] f32 -> At[n][324][128] bf16 ============
// grid 512 = 256 img x 2 y-halves; l[128*67] = 34.3 KB, 4 blocks/CU.
__global__ __launch_bounds__(256) void k_at(const float* __restrict__ in,
    unsigned short* __restrict__ At, int relu){
  __shared__ unsigned int l[128*67];     // [px_local][64 words(=128 ci)] pad 3 -> 67
  int b = blockIdx.x;
  int h = b & 1;            // y-half: px = h*128 + local
  int n = b >> 1;
  int tid = threadIdx.x;
  int pxl = tid & 127;      // local px
  int jh  = tid >> 7;       // word parity
  int pxg = h*128 + pxl;
  for (int w = jh; w < 64; w += 2){
    int j = w*2;
    float a = in[(n*128+j  )*256 + pxg];
    float bb = in[(n*128+j+1)*256 + pxg];
    if (relu){ a = relu_(a); bb = relu_(bb); }
    l[pxl*67 + w] = (unsigned int)f2bf(a) | ((unsigned int)f2bf(bb)<<16);
  }
  __syncthreads();
  unsigned short* Ab = At + (size_t)n*324*128;
  #pragma unroll
  for (int it=0; it<8; it++){
    int u = it*256 + tid;
    int px = u >> 4, seg = u & 15;     // px local 0..127
    int pxg2 = h*128 + px;
    int y = pxg2 >> 4, x = pxg2 & 15;
    int pp = (y+1)*18 + (x+1);
    uint4 v;
    v.x = l[px*67 + seg*4 + 0];
    v.y = l[px*67 + seg*4 + 1];
    v.z = l[px*67 + seg*4 + 2];
    v.w = l[px*67 + seg*4 + 3];
    *(uint4*)(Ab + pp*128 + seg*8) = v;
  }
  // halo: half h fills its boundary row (18 pp) + side cols of its 8 y-rows (16 pp) = 544 units
  uint4 z; z.x=0; z.y=0; z.z=0; z.w=0;
  for (int it=0; it<3; it++){
    int u = it*256 + tid;
    if (u >= 544) break;
    int hh = u >> 4, seg = u & 15;   // hh 0..33
    int pp;
    if (h == 0){
      if (hh < 18) pp = hh;                                      // top row 0
      else { int s = hh-18; pp = (1 + (s>>1))*18 + (s&1)*17; }   // rows 1..8 side cols
    } else {
      if (hh < 18) pp = 306 + hh;                                // bottom row 17
      else { int s = hh-18; pp = (9 + (s>>1))*18 + (s&1)*17; }   // rows 9..16 side cols
    }
    *(uint4*)(Ab + pp*128 + seg*8) = z;
  }
}

// ================= MFMA 3x3 conv with LDS-staged A panel ========================================
template<int CO>
__global__ __launch_bounds__(512) void k_c3mfma(const unsigned short* __restrict__ At,
    const unsigned short* __restrict__ Wt, const float* __restrict__ bias,
    float* __restrict__ out){
  constexpr int WNW = (CO==128) ? 2 : 1;   // waves along N
  constexpr int WMW = 8/WNW;               // waves along M
  constexpr int MT  = 16/WMW;              // m-tiles per wave
  constexpr int NT  = (CO/16)/WNW;         // n-tiles per wave
  __shared__ short8 lA[16][324];           // 82944 B
  int n = blockIdx.x;
  int tid = threadIdx.x;
  const short8* src = (const short8*)(At + (size_t)n*324*128);
  #pragma unroll
  for (int it=0; it<11; it++){
    int u = it*512 + tid;
    if (u < 5184) lA[u & 15][u >> 4] = src[u];
  }
  __syncthreads();
  int wid = tid >> 6, lane = tid & 63;
  int wn = wid % WNW, wm = wid / WNW;
  int lrow = lane & 15, lkb = lane >> 4;
  f32x4 acc[MT][NT];
  #pragma unroll
  for (int i=0;i<MT;i++)
    #pragma unroll
    for (int j=0;j<NT;j++){ acc[i][j].x=0.f; acc[i][j].y=0.f; acc[i][j].z=0.f; acc[i][j].w=0.f; }
  for (int t=0; t<9; t++){
    int ky = t/3, kx = t - 3*(t/3);
    #pragma unroll
    for (int kc=0; kc<4; kc++){
      int ch = kc*4 + lkb;
      int k0 = kc*32 + lkb*8;
      short8 a[MT], b[NT];
      #pragma unroll
      for (int i=0;i<MT;i++){
        int m = wm*(MT*16) + i*16 + lrow;
        int y = m >> 4, x = m & 15;
        int pp = (y+ky)*18 + (x+kx);
        a[i] = lA[ch][pp];
      }
      #pragma unroll
      for (int j=0;j<NT;j++){
        int co = wn*(NT*16) + j*16 + lrow;
        b[j] = *(const short8*)(Wt + (t*CO + co)*128 + k0);
      }
      #pragma unroll
      for (int i=0;i<MT;i++)
        #pragma unroll
        for (int j=0;j<NT;j++)
          acc[i][j] = __builtin_amdgcn_mfma_f32_16x16x32_bf16(a[i], b[j], acc[i][j], 0,0,0);
    }
  }
  #pragma unroll
  for (int j=0;j<NT;j++){
    int co = wn*(NT*16) + j*16 + lrow;
    float bv = bias[co];
    #pragma unroll
    for (int i=0;i<MT;i++){
      int px0 = wm*(MT*16) + i*16 + lkb*4;
      f32x4 v = acc[i][j];
      v.x += bv; v.y += bv; v.z += bv; v.w += bv;
      *(f32x4*)(out + ((size_t)n*CO+co)*256 + px0) = v;
    }
  }
}

// ================= deconv1 MFMA with LDS-staged panel: 2 parity classes per block ===============
__global__ __launch_bounds__(512) void k_dc1mfma(const unsigned short* __restrict__ At,
    const unsigned short* __restrict__ Wt, const float* __restrict__ bias,
    float* __restrict__ out){
  __shared__ short8 lA[16][324];           // 82944 B
  int b = blockIdx.x;
  int wsw = (b & 7)*64 + (b >> 3);         // grid 512, 8 XCDs: image-halves co-located
  int half = wsw & 1;
  int n    = wsw >> 1;
  int tid = threadIdx.x;
  const short8* src = (const short8*)(At + (size_t)n*324*128);
  #pragma unroll
  for (int it=0; it<11; it++){
    int u = it*512 + tid;
    if (u < 5184) lA[u & 15][u >> 4] = src[u];
  }
  __syncthreads();
  int wid = tid >> 6, lane = tid & 63;
  int cls = half*2 + (wid >> 2);
  int wm  = wid & 3;
  int p_y = cls >> 1, p_x = cls & 1;
  int lrow = lane & 15, lkb = lane >> 4;
  f32x4 acc[4][4];
  #pragma unroll
  for (int i=0;i<4;i++)
    #pragma unroll
    for (int j=0;j<4;j++){ acc[i][j].x=0.f; acc[i][j].y=0.f; acc[i][j].z=0.f; acc[i][j].w=0.f; }
  #pragma unroll
  for (int kc=0; kc<16; kc++){
    int tapi = kc >> 2;                 // a*2+b
    int a = tapi >> 1, bb = tapi & 1;
    int ch = (kc & 3)*4 + lkb;
    int k0 = (kc & 3)*32 + lkb*8;
    int t = (p_y + 2*a)*4 + (p_x + 2*bb);
    short8 av[4], bv[4];
    #pragma unroll
    for (int i=0;i<4;i++){
      int m = wm*64 + i*16 + lrow;
      int gy = m >> 4, gx = m & 15;
      int pp = (gy + p_y + a)*18 + (gx + p_x + bb);
      av[i] = lA[ch][pp];
    }
    #pragma unroll
    for (int j=0;j<4;j++){
      int co = j*16 + lrow;
      bv[j] = *(const short8*)(Wt + (t*64 + co)*128 + k0);
    }
    #pragma unroll
    for (int i=0;i<4;i++)
      #pragma unroll
      for (int j=0;j<4;j++)
        acc[i][j] = __builtin_amdgcn_mfma_f32_16x16x32_bf16(av[i], bv[j], acc[i][j], 0,0,0);
  }
  #pragma unroll
  for (int j=0;j<4;j++){
    int co = j*16 + lrow;
    float bvf = bias[co];
    float* op = out + (((size_t)n*64 + co)*4 + cls)*256;
    #pragma unroll
    for (int i=0;i<4;i++){
      int m0 = wm*64 + i*16 + lkb*4;
      f32x4 v = acc[i][j];
      v.x = relu_(v.x + bvf); v.y = relu_(v.y + bvf);
      v.z = relu_(v.z + bvf); v.w = relu_(v.w + bvf);
      *(f32x4*)(op + m0) = v;
    }
  }
}

// ================= residual 1x1: h += b + W2 @ relu(r);  co-half split, XCD co-located ==========
// grid 512 = 256 img x 2 co-halves; each block does 64 co.
__global__ __launch_bounds__(256) void k_res1x1(const float* __restrict__ r,
    const float* __restrict__ w, const float* __restrict__ bias, float* __restrict__ h){
  int b = blockIdx.x;
  int wsw = (b & 7)*64 + (b >> 3);
  int coh = wsw & 1;
  int n   = wsw >> 1;
  int tid = threadIdx.x;
  float rv[32];
  #pragma unroll
  for (int ci=0;ci<32;ci++) rv[ci] = relu_(r[(n*32+ci)*256 + tid]);
  int co0 = coh*64;
  for (int co=co0;co<co0+64;co++){
    float a = bias[co];
    const float* wp = w + co*32;
    #pragma unroll
    for (int ci=0;ci<32;ci++) a += rv[ci]*wp[ci];
    h[(n*128+co)*256 + tid] += a;
  }
}

// ================= generic f32 -> bf16 (optional relu), float4 granularity ======================
__global__ __launch_bounds__(256) void k_f2b(const float* __restrict__ in,
    unsigned short* __restrict__ out, int n4, int relu){
  int i = blockIdx.x*256 + threadIdx.x;
  if (i >= n4) return;
  float4 v = ((const float4*)in)[i];
  if (relu){ v.x=relu_(v.x); v.y=relu_(v.y); v.z=relu_(v.z); v.w=relu_(v.w); }
  uint2 o;
  o.x = (unsigned int)f2bf(v.x) | ((unsigned int)f2bf(v.y)<<16);
  o.y = (unsigned int)f2bf(v.z) | ((unsigned int)f2bf(v.w)<<16);
  ((uint2*)out)[i] = o;
}

// ================= decfc W transpose: w[256 k][32768 j] f32 -> Wt[j][256 k] bf16 ================
__global__ __launch_bounds__(256) void k_wtd(const float* __restrict__ w,
    unsigned short* __restrict__ Wt){
  __shared__ unsigned int l[256*65];     // [j][64 words(=128 k)+1]
  int j0 = blockIdx.x*256;               // grid 128
  int tid = threadIdx.x;
  for (int half=0; half<2; half++){
    __syncthreads();
    int kb = half*128;
    for (int k=0;k<128;k+=2){
      float a = w[(size_t)(kb+k  )*32768 + j0 + tid];
      float b = w[(size_t)(kb+k+1)*32768 + j0 + tid];
      l[tid*65 + (k>>1)] = (unsigned int)f2bf(a) | ((unsigned int)f2bf(b)<<16);
    }
    __syncthreads();
    #pragma unroll
    for (int it=0; it<16; it++){
      int u = it*256 + tid;
      int j = u >> 4, seg = u & 15;
      uint4 v;
      v.x = l[j*65 + seg*4 + 0];
      v.y = l[j*65 + seg*4 + 1];
      v.z = l[j*65 + seg*4 + 2];
      v.w = l[j*65 + seg*4 + 3];
      *(uint4*)(Wt + (size_t)(j0+j)*256 + kb + seg*8) = v;
    }
  }
}

// ================= encfc W transpose: w[32768 k][256 d] f32 -> Wt[(dbase+d)][32768 k] bf16 ======
__global__ __launch_bounds__(256) void k_wtfc(const float* __restrict__ w,
    unsigned short* __restrict__ Wt, int dbase){
  __shared__ unsigned int l[256*65];     // [d][64 words(=128 k)+1]
  int k0 = blockIdx.x*256;               // grid 128
  int tid = threadIdx.x;
  for (int half=0; half<2; half++){
    __syncthreads();
    int kb = half*128;
    for (int k=0;k<128;k+=2){
      float a = w[(size_t)(k0+kb+k  )*256 + tid];
      float b = w[(size_t)(k0+kb+k+1)*256 + tid];
      l[tid*65 + (k>>1)] = (unsigned int)f2bf(a) | ((unsigned int)f2bf(b)<<16);
    }
    __syncthreads();
    #pragma unroll
    for (int it=0; it<16; it++){
      int u = it*256 + tid;
      int d = u >> 4, seg = u & 15;
      uint4 v;
      v.x = l[d*65 + seg*4 + 0];
      v.y = l[d*65 + seg*4 + 1];
      v.z = l[d*65 + seg*4 + 2];
      v.w = l[d*65 + seg*4 + 3];
      *(uint4*)(Wt + (size_t)(dbase+d)*32768 + k0 + kb + seg*8) = v;
    }
  }
}

// ================= decfc MFMA: hd[m=256][j=32768] = zb * Wtd + b ================================
__global__ __launch_bounds__(512) void k_dfmfma(const unsigned short* __restrict__ zb,
    const unsigned short* __restrict__ Wt, const float* __restrict__ bias,
    float* __restrict__ hd){
  int jbase = blockIdx.x*128;
  int tid = threadIdx.x;
  int wid = tid >> 6, lane = tid & 63;
  int wn = wid & 1, wm = wid >> 1;
  int lrow = lane & 15, lkb = lane >> 4;
  f32x4 acc[4][4];
  #pragma unroll
  for (int i=0;i<4;i++)
    #pragma unroll
    for (int j=0;j<4;j++){ acc[i][j].x=0.f; acc[i][j].y=0.f; acc[i][j].z=0.f; acc[i][j].w=0.f; }
  #pragma unroll
  for (int kc=0; kc<8; kc++){
    int k0 = kc*32 + lkb*8;
    short8 a[4], b[4];
    #pragma unroll
    for (int i=0;i<4;i++){
      int m = wm*64 + i*16 + lrow;
      a[i] = *(const short8*)(zb + m*256 + k0);
    }
    #pragma unroll
    for (int j=0;j<4;j++){
      int jj = jbase + wn*64 + j*16 + lrow;
      b[j] = *(const short8*)(Wt + (size_t)jj*256 + k0);
    }
    #pragma unroll
    for (int i=0;i<4;i++)
      #pragma unroll
      for (int j=0;j<4;j++)
        acc[i][j] = __builtin_amdgcn_mfma_f32_16x16x32_bf16(a[i], b[j], acc[i][j], 0,0,0);
  }
  #pragma unroll
  for (int j=0;j<4;j++){
    int jj = jbase + wn*64 + j*16 + lrow;
    float bv = bias[jj];
    #pragma unroll
    for (int i=0;i<4;i++){
      int m0 = wm*64 + i*16 + lkb*4;
      f32x4 v = acc[i][j];
      hd[(size_t)(m0  )*32768 + jj] = v.x + bv;
      hd[(size_t)(m0+1)*32768 + jj] = v.y + bv;
      hd[(size_t)(m0+2)*32768 + jj] = v.z + bv;
      hd[(size_t)(m0+3)*32768 + jj] = v.w + bv;
    }
  }
}

// ================= encfc MFMA: P[ks][m=256][n=512] partials, K-split 64 x 512 ===================
__global__ __launch_bounds__(512) void k_efmfma(const unsigned short* __restrict__ Ab,
    const unsigned short* __restrict__ Wt, float* __restrict__ P){
  int ks = blockIdx.x >> 2;
  int ng = blockIdx.x & 3;
  int kchunk = ks*512;
  int tid = threadIdx.x;
  int wid = tid >> 6, lane = tid & 63;
  int wn = wid & 1, wm = wid >> 1;
  int lrow = lane & 15, lkb = lane >> 4;
  f32x4 acc[4][4];
  #pragma unroll
  for (int i=0;i<4;i++)
    #pragma unroll
    for (int j=0;j<4;j++){ acc[i][j].x=0.f; acc[i][j].y=0.f; acc[i][j].z=0.f; acc[i][j].w=0.f; }
  #pragma unroll
  for (int kc=0; kc<16; kc++){
    int k0 = kchunk + kc*32 + lkb*8;
    short8 a[4], b[4];
    #pragma unroll
    for (int i=0;i<4;i++){
      int m = wm*64 + i*16 + lrow;
      a[i] = *(const short8*)(Ab + (size_t)m*32768 + k0);
    }
    #pragma unroll
    for (int j=0;j<4;j++){
      int n = ng*128 + wn*64 + j*16 + lrow;
      b[j] = *(const short8*)(Wt + (size_t)n*32768 + k0);
    }
    #pragma unroll
    for (int i=0;i<4;i++)
      #pragma unroll
      for (int j=0;j<4;j++)
        acc[i][j] = __builtin_amdgcn_mfma_f32_16x16x32_bf16(a[i], b[j], acc[i][j], 0,0,0);
  }
  #pragma unroll
  for (int j=0;j<4;j++){
    int n = ng*128 + wn*64 + j*16 + lrow;
    #pragma unroll
    for (int i=0;i<4;i++){
      int m0 = wm*64 + i*16 + lkb*4;
      f32x4 v = acc[i][j];
      P[((size_t)ks*256 + m0  )*512 + n] = v.x;
      P[((size_t)ks*256 + m0+1)*512 + n] = v.y;
      P[((size_t)ks*256 + m0+2)*512 + n] = v.z;
      P[((size_t)ks*256 + m0+3)*512 + n] = v.w;
    }
  }
}

__global__ __launch_bounds__(256) void k_efred(const float* __restrict__ P,
    const float* __restrict__ bmu, const float* __restrict__ blv,
    float* __restrict__ mu, float* __restrict__ lv){
  int idx = blockIdx.x*256 + threadIdx.x;   // 65536
  int m = idx >> 8, d = idx & 255;
  float sm=0.f, sl=0.f;
  for (int ks=0; ks<64; ks++){
    size_t base = ((size_t)ks*256 + m)*512;
    sm += P[base + d];
    sl += P[base + 256 + d];
  }
  mu[idx] = sm + bmu[d];
  lv[idx] = sl + blv[d];
}

// ================= chain GCN helpers ==========================
__global__ void k_deg(const int* __restrict__ ei, int ne, float* __restrict__ deg,
                      float* __restrict__ dinv){
  int n = threadIdx.x;                       // 1 block x 256
  const int* dst = ei + ne;
  int c = 1;
  for (int e=0;e<ne;e++) c += (dst[e]==n) ? 1 : 0;
  deg[n]  = (float)c;
  dinv[n] = rsqrtf((float)c);
}

// gemm256 + zero agg fused (same grid covers both)
__global__ __launch_bounds__(256) void k_gemm256(const float* __restrict__ v,
    const float* __restrict__ w, float* __restrict__ xl, float* __restrict__ agg){
  __shared__ float vl[256];
  int n = blockIdx.x, tid = threadIdx.x;
  vl[tid] = v[(n<<8)+tid];
  agg[(n<<8)+tid] = 0.f;
  __syncthreads();
  float a=0.f;
  for (int k=0;k<256;k++) a += vl[k]*w[(k<<8)+tid];
  xl[(n<<8)+tid]=a;
}

__global__ __launch_bounds__(256) void k_edge(const int* __restrict__ ei, int ne,
    const float* __restrict__ xl, const float* __restrict__ dinv, float* __restrict__ agg){
  int e = blockIdx.x, d = threadIdx.x;
  int s = ei[e], t = ei[ne+e];
  float c = dinv[s]*dinv[t];
  atomicAdd(&agg[(t<<8)+d], xl[(s<<8)+d]*c);
}

__global__ __launch_bounds__(256) void k_gcnout(const float* __restrict__ agg,
    const float* __restrict__ xl, const float* __restrict__ deg, const float* __restrict__ bias,
    float* __restrict__ vout, float* __restrict__ vout2){
  int idx = blockIdx.x*256 + threadIdx.x;
  int n = idx>>8, d = idx&255;
  float o = relu_(agg[idx] + xl[idx]/deg[n] + bias[d]);
  vout[idx]=o;
  if (vout2) vout2[idx]=o;
}

// ================= dim GNN ==========================
__global__ __launch_bounds__(256) void k_y1(const float* __restrict__ emb,
    const float* __restrict__ w, float* __restrict__ y1){
  int idx = blockIdx.x*256+threadIdx.x;   // 16384
  int i = idx>>6, h = idx&63;
  float a=0.f;
  #pragma unroll
  for (int k=0;k<16;k++) a += emb[i*16+k]*w[k*64+h];
  y1[idx]=a;
}

__global__ __launch_bounds__(256) void k_mask(const float* __restrict__ L,
    float* __restrict__ mask, float* __restrict__ rowcnt){
  __shared__ float red[256];
  int i = blockIdx.x, j = threadIdx.x;
  float m = (i!=j && (L[(i<<8)+j] + L[(j<<8)+i] > 0.f)) ? 1.f : 0.f;
  mask[(i<<8)+j]=m;
  red[j]=m; __syncthreads();
  for (int s=128;s>0;s>>=1){ if(j<s) red[j]+=red[j+s]; __syncthreads(); }
  if (j==0) rowcnt[i]=red[0];
}

__global__ __launch_bounds__(256) void k_dimdeg(const float* __restrict__ rowcnt,
    float* __restrict__ ddinv, float* __restrict__ fbflag){
  __shared__ float red[256];
  int i = threadIdx.x;
  red[i]=rowcnt[i]; __syncthreads();
  for (int s=128;s>0;s>>=1){ if(i<s) red[i]+=red[i+s]; __syncthreads(); }
  float fb = (red[0] > 0.f) ? 0.f : 1.f;
  float degi = 1.f + (fb>0.5f ? 255.f : rowcnt[i]);
  ddinv[i] = rsqrtf(degi);
  if (i==0) fbflag[0]=fb;
}

__global__ __launch_bounds__(64) void k_xd(const float* __restrict__ mask,
    const float* __restrict__ ddinv, const float* __restrict__ y1,
    const float* __restrict__ b, const float* __restrict__ fbflag, float* __restrict__ xd){
  int i = blockIdx.x, h = threadIdx.x;   // 64 threads
  float fb = fbflag[0];
  float dii = ddinv[i];
  float a=0.f;
  for (int j=0;j<256;j++){
    float ah = (j==i) ? 1.f : (fb>0.5f ? 1.f : mask[(i<<8)+j]);
    a += ah*dii*ddinv[j]*y1[(j<<6)+h];
  }
  xd[(i<<6)+h] = relu_(a + b[h]);
}

__global__ __launch_bounds__(256) void k_imp(const float* __restrict__ xd,
    const float* __restrict__ w2, const float* __restrict__ b2,
    const float* __restrict__ mask, const float* __restrict__ ddinv,
    const float* __restrict__ fbflag, float* __restrict__ imp, float* __restrict__ imp_out){
  __shared__ float t[256];
  int i = threadIdx.x;                   // 1 block x 256
  float a=0.f;
  #pragma unroll
  for (int h=0;h<64;h++) a += xd[(i<<6)+h]*w2[h];
  t[i]=a; __syncthreads();
  float fb=fbflag[0]; float dii=ddinv[i];
  float s=0.f;
  for (int j=0;j<256;j++){
    float ah = (j==i) ? 1.f : (fb>0.5f ? 1.f : mask[(i<<8)+j]);
    s += ah*dii*ddinv[j]*t[j];
  }
  float r = s + b2[0];
  imp[i]=r; imp_out[i]=r;
}

// ================= reparameterize (fused: writes z f32 + z bf16) ==========================
__global__ __launch_bounds__(256) void k_reparam(const float* __restrict__ mu,
    const float* __restrict__ lv, const float* __restrict__ eps,
    const float* __restrict__ v2, const float* __restrict__ imp, float* __restrict__ z,
    unsigned short* __restrict__ zb){
  int idx = blockIdx.x*256+threadIdx.x;   // 65536
  int d = idx&255;
  float s = expf(0.5f*lv[idx]);
  float zv = mu[idx] + s*(eps[idx]*(v2[idx]*imp[d]));
  z[idx] = zv;
  zb[idx] = f2bf(zv);
}

// ================= deconv2 + fused SSE: parity-plane in -> recon + ssep[512] ====================
// Per-parity, 8 stages of 8 ci (tile 32KB), reg prefetch + XCD swizzle + SSE epilogue.
__global__ __launch_bounds__(512) void k_deconv2(const float* __restrict__ in,
    const float* __restrict__ w, const float* __restrict__ bias, float* __restrict__ out,
    const float* __restrict__ xin, float* __restrict__ ssep){
  __shared__ float tile[8192];         // 8 ci x 1024 px
  __shared__ float red[512];
  int b = blockIdx.x;
  int wsw = (b & 7)*64 + (b >> 3);     // 8 XCDs: both parities of an image on one XCD
  int p_x = wsw & 1;
  int n   = wsw >> 1;
  int tid = threadIdx.x;
  int xi = tid & 31, yb = tid >> 5;    // yb 0..15
  int x = 2*xi + p_x;
  int ix0 = xi + p_x - 1, ix1 = xi + p_x;
  bool okx0 = (unsigned)ix0 < 32u, okx1 = (unsigned)ix1 < 32u;
  int r0 = 2*yb - 1;                   // row window r0..r0+3
  int su[16], scil[16];
  #pragma unroll
  for (int t=0;t<16;t++){
    int u = t*512 + tid;
    int px = u & 1023;
    int r = px >> 5, c = px & 31;
    su[t] = (((r&1)<<1)|(c&1))*256 + ((r>>1)<<4) + (c>>1);
    scil[t] = u >> 10;
  }
  float acc[4][3];
  #pragma unroll
  for (int r=0;r<4;r++)
    #pragma unroll
    for (int c=0;c<3;c++) acc[r][c]=0.f;
  const float* ip0 = in + (size_t)n*65536;
  float rg[16];
  #pragma unroll
  for (int t=0;t<16;t++) rg[t] = ip0[(size_t)scil[t]*1024 + su[t]];
  for (int c0=0; c0<64; c0+=8){
    __syncthreads();
    #pragma unroll
    for (int t=0;t<16;t++) tile[t*512 + tid] = rg[t];
    __syncthreads();
    if (c0+8 < 64){
      #pragma unroll
      for (int t=0;t<16;t++) rg[t] = ip0[(size_t)(c0+8+scil[t])*1024 + su[t]];
    }
    #pragma unroll
    for (int cil=0; cil<8; cil++){
      const float* tl = tile + cil*1024;
      float tv[4][2];
      #pragma unroll
      for (int rr=0; rr<4; rr++){
        int row = r0 + rr;
        bool okr = (unsigned)row < 32u;
        tv[rr][0] = (okr && okx0) ? tl[row*32+ix0] : 0.f;
        tv[rr][1] = (okr && okx1) ? tl[row*32+ix1] : 0.f;
      }
      const float* wp = w + (c0+cil)*3;
      #pragma unroll
      for (int r=0;r<4;r++){
        int py = r & 1;
        int rA = (r==0)?0:((r==3)?2:1);
        int rB = (r==0)?1:((r==3)?3:2);
        #pragma unroll
        for (int bb=0;bb<2;bb++){
          int kx = p_x + 2*bb;
          const float* w0 = wp + (py*4+kx)*192;        // ky = py
          const float* w1 = wp + ((py+2)*4+kx)*192;    // ky = py+2
          float vA = tv[rA][bb], vB = tv[rB][bb];
          #pragma unroll
          for (int c=0;c<3;c++){
            acc[r][c] += vA * w0[c];
            acc[r][c] += vB * w1[c];
          }
        }
      }
    }
  }
  float sse_l = 0.f;
  #pragma unroll
  for (int c=0;c<3;c++){
    float bv = bias[c];
    #pragma unroll
    for (int r=0;r<4;r++){
      int y = 4*yb + r;
      size_t oi = (((size_t)n*3+c)*64 + y)*64 + x;
      float v = acc[r][c] + bv;
      out[oi] = v;
      float d = v - xin[oi];
      sse_l += d*d;
    }
  }
  red[tid] = sse_l; __syncthreads();
  for (int s=256;s>0;s>>=1){ if(tid<s) red[tid]+=red[tid+s]; __syncthreads(); }
  if (tid==0) ssep[b] = red[0];
}

// ================= reductions ==========================
__global__ __launch_bounds__(256) void k_stats(const float* __restrict__ mu,
    const float* __restrict__ lv, const float* __restrict__ z,
    float* __restrict__ z2part, float* __restrict__ entpart, float* __restrict__ klflag){
  __shared__ float r1[256], r2[256], r3[256];
  int d = blockIdx.x, n = threadIdx.x;
  int idx = (n<<8) + d;
  float m = mu[idx], l = lv[idx], zz = z[idx];
  float s2e = expf(l) + 1e-8f;
  float leps = logf(s2e);
  r1[n] = zz*zz;
  r2[n] = 1.f + leps;
  r3[n] = -0.5f*(1.f + leps - m*m - s2e);
  __syncthreads();
  for (int s=128;s>0;s>>=1){
    if (n<s){ r1[n]+=r1[n+s]; r2[n]+=r2[n+s]; r3[n]+=r3[n+s]; }
    __syncthreads();
  }
  if (n==0){
    z2part[d]=r1[0]; entpart[d]=r2[0];
    klflag[d] = (r3[0]*(1.f/256.f) > 0.01f) ? 1.f : 0.f;
  }
}

__global__ __launch_bounds__(256) void k_final(const float* __restrict__ ssepart,
    const float* __restrict__ z2part, const float* __restrict__ entpart,
    const float* __restrict__ klflag, float* __restrict__ out){
  __shared__ float red[256];
  int tid = threadIdx.x;
  float s=0.f;
  for (int i=tid;i<512;i+=256) s += ssepart[i];
  red[tid]=s; __syncthreads();
  for (int st=128;st>0;st>>=1){ if(tid<st) red[tid]+=red[tid+st]; __syncthreads(); }
  float sse = red[0]; __syncthreads();
  red[tid]=z2part[tid]; __syncthreads();
  for (int st=128;st>0;st>>=1){ if(tid<st) red[tid]+=red[tid+st]; __syncthreads(); }
  float z2 = red[0]; __syncthreads();
  red[tid]=entpart[tid]; __syncthreads();
  for (int st=128;st>0;st>>=1){ if(tid<st) red[tid]+=red[tid+st]; __syncthreads(); }
  float ent = red[0]; __syncthreads();
  red[tid]=klflag[tid]; __syncthreads();
  for (int st=128;st>0;st>>=1){ if(tid<st) red[tid]+=red[tid+st]; __syncthreads(); }
  if (tid==0){
    float logpxz  = -sse;
    float prior   = -0.5f*(z2 + 65536.f*1.8378770664093453f);
    float entropy = 0.5f*ent;
    out[OUT_ELBO] = logpxz + prior + entropy;
    out[OUT_NACT] = red[0];
  }
}

// ======================================================================================
extern "C" void kernel_launch(void* const* d_in, const int* in_sizes, int n_in,
                              void* d_out, int out_size, void* d_ws, size_t ws_size,
                              hipStream_t stream){
  const float* x    = (const float*)d_in[0];
  const float* eps  = (const float*)d_in[1];
  const int*   ei   = (const int*)d_in[2];
  const float* c1w  = (const float*)d_in[3];
  const float* c1b  = (const float*)d_in[4];
  const float* c2w  = (const float*)d_in[5];
  const float* c2b  = (const float*)d_in[6];
  const float* c3w  = (const float*)d_in[7];
  const float* c3b  = (const float*)d_in[8];
  const float* erw1 = (const float*)d_in[9];
  const float* erb1 = (const float*)d_in[10];
  const float* erw2 = (const float*)d_in[11];
  const float* erb2 = (const float*)d_in[12];
  const float* fmw  = (const float*)d_in[13];
  const float* fmb  = (const float*)d_in[14];
  const float* flw  = (const float*)d_in[15];
  const float* flb  = (const float*)d_in[16];
  const float* dfw  = (const float*)d_in[17];
  const float* dfb  = (const float*)d_in[18];
  const float* drw1 = (const float*)d_in[19];
  const float* drb1 = (const float*)d_in[20];
  const float* drw2 = (const float*)d_in[21];
  const float* drb2 = (const float*)d_in[22];
  const float* t1w  = (const float*)d_in[23];
  const float* t1b  = (const float*)d_in[24];
  const float* t2w  = (const float*)d_in[25];
  const float* t2b  = (const float*)d_in[26];
  const float* iw   = (const float*)d_in[27];
  const float* ib   = (const float*)d_in[28];
  const float* Lg   = (const float*)d_in[29];
  const float* emb  = (const float*)d_in[30];
  const float* g1w  = (const float*)d_in[31];
  const float* g1b  = (const float*)d_in[32];
  const float* g2w  = (const float*)d_in[33];
  const float* g2b  = (const float*)d_in[34];
  float* out = (float*)d_out;
  float* ws  = (float*)d_ws;
  int ne = in_sizes[2] / 2;   // 510

  // workspace layout (floats); total ~34.1M floats (~137 MB)
  float* A  = ws;                    // 16777216: h1, later deconv1 output (parity planes)
  float* Bb = ws + 16777216;         //  8388608: h2; encfc Wtfc bf16; later hd (decoder)
  float* Cc = Bb + 8388608;          //  8388608: h3 (encoder); conv2/decfc/deconv1 scratch
  float* Rr = A;                     //  2097152: res temp (aliases A[0..2M))
  float* P  = A + 2097152;           //  8388608: encfc MFMA partials [64][256][512]
  unsigned short* At = (unsigned short*)(A + 10485760);   // conv3 act bf16 (A dead then)
  unsigned short* Ab = (unsigned short*)(A + 10485760);   // encfc act bf16 (same region, seq use)
  unsigned short* Wt = (unsigned short*)(A + 15794176);   // conv3 wt bf16
  unsigned short* At2 = (unsigned short*)Cc;              // conv2 act bf16 (Cc free then)
  unsigned short* Wt2 = (unsigned short*)(Cc + 5242880);  // conv2 wt bf16
  unsigned short* Wtd = (unsigned short*)Cc;              // decfc W bf16 (Cc free at decode)
  unsigned short* Atd = (unsigned short*)Cc;              // deconv1 act bf16 (after decfc)
  unsigned short* Wt1 = (unsigned short*)(Cc + 5308416);  // deconv1 wt bf16
  unsigned short* Wtfc = (unsigned short*)Bb;             // encfc W bf16 [512][32768]
  float* S  = Cc + 8388608;
  float* mu     = S; S += 65536;
  float* lv     = S; S += 65536;
  float* v1     = S; S += 65536;
  float* v2     = S; S += 65536;
  float* xl     = S; S += 65536;
  float* agg    = S; S += 65536;
  float* zz     = S; S += 65536;
  float* mask   = S; S += 65536;
  float* y1     = S; S += 16384;
  float* xd     = S; S += 16384;
  float* zbf    = S; S += 32768;     // z bf16 (65536 bf16)
  float* deg    = S; S += 256;
  float* dinvb  = S; S += 256;
  float* rowcnt = S; S += 256;
  float* ddinv  = S; S += 256;
  float* fbflag = S; S += 256;
  float* impv   = S; S += 256;
  float* ssep   = S; S += 1024;
  float* z2p    = S; S += 256;
  float* entp   = S; S += 256;
  float* klf    = S; S += 256;
  unsigned short* zb = (unsigned short*)zbf;

  // ---- encoder ----
  k_conv1<<<512,512,0,stream>>>(x, c1w, c1b, A);
  // conv2 via MFMA, two 128-image passes (At2 scratch lives in Cc, dead until conv3)
  k_wt2<<<512,256,0,stream>>>(c2w, Wt2);
  for (int pass=0; pass<2; pass++){
    size_t n0 = (size_t)pass*128;
    k_at2<<<512,256,0,stream>>>(A + n0*65536, At2);
    k_c2mfma<<<256,256,0,stream>>>(At2, Wt2, c2b, Bb + n0*32768);
  }
  // enc conv3 (Co=128) via MFMA (LDS-staged A)
  k_wt<<<576,256,0,stream>>>(c3w, Wt, 128);
  k_at<<<512,256,0,stream>>>(Bb, At, 0);
  k_c3mfma<128><<<256,512,0,stream>>>(At, Wt, c3b, Cc);
  // enc res layer 0
  k_wt<<<144,256,0,stream>>>(erw1, Wt, 32);
  k_at<<<512,256,0,stream>>>(Cc, At, 1);
  k_c3mfma<32><<<256,512,0,stream>>>(At, Wt, erb1, Rr);
  k_res1x1<<<512,256,0,stream>>>(Rr, erw2, erb2, Cc);
  // enc res layer 1
  k_wt<<<144,256,0,stream>>>(erw1+36864, Wt, 32);
  k_at<<<512,256,0,stream>>>(Cc, At, 1);
  k_c3mfma<32><<<256,512,0,stream>>>(At, Wt, erb1+32, Rr);
  k_res1x1<<<512,256,0,stream>>>(Rr, erw2+4096, erb2+128, Cc);
  // encfc via MFMA: Ab = relu(Cc) bf16; Wtfc = [Wmu|Wlv]^T bf16 (in Bb, dead now)
  k_f2b<<<8192,256,0,stream>>>(Cc, Ab, 2097152, 1);
  k_wtfc<<<128,256,0,stream>>>(fmw, Wtfc, 0);
  k_wtfc<<<128,256,0,stream>>>(flw, Wtfc, 256);
  k_efmfma<<<256,512,0,stream>>>(Ab, Wtfc, P);
  k_efred<<<256,256,0,stream>>>(P, fmb, flb, mu, lv);

  // ---- instance GCN (2 layers, chain graph) ----
  k_deg<<<1,256,0,stream>>>(ei, ne, deg, dinvb);
  k_gemm256<<<256,256,0,stream>>>(mu, iw, xl, agg);
  k_edge<<<ne,256,0,stream>>>(ei, ne, xl, dinvb, agg);
  k_gcnout<<<256,256,0,stream>>>(agg, xl, deg, ib, v1, nullptr);
  k_gemm256<<<256,256,0,stream>>>(v1, iw+65536, xl, agg);
  k_edge<<<ne,256,0,stream>>>(ei, ne, xl, dinvb, agg);
  k_gcnout<<<256,256,0,stream>>>(agg, xl, deg, ib+256, v2, out + OUT_VINST);

  // ---- dim GNN ----
  k_y1<<<64,256,0,stream>>>(emb, g1w, y1);
  k_mask<<<256,256,0,stream>>>(Lg, mask, rowcnt);
  k_dimdeg<<<1,256,0,stream>>>(rowcnt, ddinv, fbflag);
  k_xd<<<256,64,0,stream>>>(mask, ddinv, y1, g1b, fbflag, xd);
  k_imp<<<1,256,0,stream>>>(xd, g2w, g2b, mask, ddinv, fbflag, impv, out + OUT_IMP);

  // ---- reparameterize + decode ----
  k_reparam<<<256,256,0,stream>>>(mu, lv, eps, v2, impv, zz, zb);
  // decfc via MFMA: Wtd = W^T bf16 (Cc region, free now)
  k_wtd<<<128,256,0,stream>>>(dfw, Wtd);
  k_dfmfma<<<256,512,0,stream>>>(zb, Wtd, dfb, Bb);
  // dec res layer 0
  k_wt<<<144,256,0,stream>>>(drw1, Wt, 32);
  k_at<<<512,256,0,stream>>>(Bb, At, 1);
  k_c3mfma<32><<<256,512,0,stream>>>(At, Wt, drb1, Rr);
  k_res1x1<<<512,256,0,stream>>>(Rr, drw2, drb2, Bb);
  // dec res layer 1
  k_wt<<<144,256,0,stream>>>(drw1+36864, Wt, 32);
  k_at<<<512,256,0,stream>>>(Bb, At, 1);
  k_c3mfma<32><<<256,512,0,stream>>>(At, Wt, drb1+32, Rr);
  k_res1x1<<<512,256,0,stream>>>(Rr, drw2+4096, drb2+128, Bb);
  // deconv1 via MFMA (LDS-staged panel, 2 parity classes per block, XCD-swizzled)
  k_wt1<<<512,256,0,stream>>>(t1w, Wt1);
  k_at<<<512,256,0,stream>>>(Bb, Atd, 1);
  k_dc1mfma<<<512,512,0,stream>>>(Atd, Wt1, t1b, A);
  k_deconv2<<<512,512,0,stream>>>(A, t2w, t2b, out, x, ssep);

  // ---- losses / stats ----
  k_stats<<<256,256,0,stream>>>(mu, lv, zz, z2p, entp, klf);
  k_final<<<1,256,0,stream>>>(ssep, z2p, entp, klf, out);
}

// Round 31
// 806.182 us; speedup vs baseline: 1.0311x; 1.0311x over previous
//
#include <hip/hip_runtime.h>
#include <math.h>

// ---- problem constants (B=256, C=3, H=64, D=256, E=16, Hg=64, R=32, L=2, hid=128) ----
#define OUT_ELBO  3145728
#define OUT_NACT  3145729
#define OUT_IMP   3145730
#define OUT_VINST 3145986

__device__ __forceinline__ float relu_(float v){ return fmaxf(v, 0.f); }

__device__ __forceinline__ unsigned short f2bf(float f){
  unsigned int u = __float_as_uint(f);
  unsigned int r = (u + 0x7FFFu + ((u>>16)&1u)) >> 16;
  return (unsigned short)r;
}

typedef __attribute__((ext_vector_type(8))) short short8;
typedef __attribute__((ext_vector_type(4))) float f32x4;

// ================= encoder conv1: (256,3,64,64) -> (256,64,32,32), k4 s2 p1, ReLU =================
__global__ __launch_bounds__(512) void k_conv1(const float* __restrict__ in,
    const float* __restrict__ w, const float* __restrict__ bias, float* __restrict__ out){
  __shared__ float li[13068];          // 3 * 66*66
  __shared__ float lw[1536];           // 48 taps * 32 co
  int cohalf = blockIdx.x & 1;
  int n      = blockIdx.x >> 1;
  int co0 = cohalf*32;
  int tid = threadIdx.x;
  for (int i=tid; i<13068; i+=512) li[i] = 0.f;
  __syncthreads();
  const float* ip = in + (size_t)n*12288;
  for (int i=tid; i<12288; i+=512){
    int ci = i >> 12, rem = i & 4095;
    int yy = rem >> 6, xx = rem & 63;
    li[ci*4356 + (yy+1)*66 + xx+1] = ip[i];
  }
  for (int i=tid; i<1536; i+=512){
    int t = i >> 5, c = i & 31;
    lw[i] = w[(co0+c)*48 + t];
  }
  __syncthreads();
  int x = tid & 31, y8 = tid >> 5;     // y8 in [0,16)
  #pragma unroll
  for (int cc=0; cc<4; cc++){
    float acc[2][8];
    #pragma unroll
    for (int q=0;q<2;q++)
      #pragma unroll
      for (int c=0;c<8;c++) acc[q][c]=0.f;
    #pragma unroll
    for (int ci=0; ci<3; ci++){
      int cb = ci*4356;
      #pragma unroll
      for (int ky=0; ky<4; ky++){
        float v[2][4];
        #pragma unroll
        for (int q=0;q<2;q++){
          int y = y8 + 16*q;
          int rb = cb + (2*y+ky)*66 + 2*x;
          v[q][0]=li[rb]; v[q][1]=li[rb+1]; v[q][2]=li[rb+2]; v[q][3]=li[rb+3];
        }
        float wv[4][8];
        #pragma unroll
        for (int kx=0;kx<4;kx++){
          int wb = ((ci*4+ky)*4+kx)*32 + cc*8;
          #pragma unroll
          for (int c=0;c<8;c++) wv[kx][c] = lw[wb+c];
        }
        #pragma unroll
        for (int q=0;q<2;q++)
          #pragma unroll
          for (int kx=0;kx<4;kx++)
            #pragma unroll
            for (int c=0;c<8;c++)
              acc[q][c] += v[q][kx]*wv[kx][c];
      }
    }
    #pragma unroll
    for (int c=0;c<8;c++){
      int co = co0 + cc*8 + c;
      float bv = bias[co];
      #pragma unroll
      for (int q=0;q<2;q++){
        int y = y8 + 16*q;
        out[(((size_t)n*64+co)*32 + y)*32 + x] = relu_(acc[q][c] + bv);
      }
    }
  }
}

// ================= conv2 weights: w[co][ci][t] f32 (128,64,16) -> Wt2[t][co][ci] bf16 ============
__global__ __launch_bounds__(256) void k_wt2(const float* __restrict__ w,
    unsigned short* __restrict__ Wt){
  int idx = blockIdx.x*256 + threadIdx.x;   // 131072 total
  int ci = idx & 63;
  int r = idx >> 6;          // t*128 + co
  int t = r >> 7, co = r & 127;
  Wt[idx] = f2bf(w[((co*64 + ci)<<4) + t]);
}

// ================= conv2 act transpose: in[n][64][1024] f32 -> At2[n][34*34][64] bf16 ===========
// grid 512 = 128 img x 4 px-chunks; 33.8 KB LDS, 4 blocks/CU.
__global__ __launch_bounds__(256) void k_at2(const float* __restrict__ in,
    unsigned short* __restrict__ At){
  __shared__ unsigned int l[256*33];     // 256 px x 32 words (64 ci), pad->33
  int b = blockIdx.x;
  int c = b & 3;
  int n = b >> 2;
  int tid = threadIdx.x;
  const float* ip = in + (size_t)n*65536;
  unsigned short* Ab = At + (size_t)n*1156*64;
  int pxg = c*256 + tid;
  for (int j=0;j<64;j+=2){
    float a = ip[j*1024 + pxg];
    float bb = ip[(j+1)*1024 + pxg];
    l[tid*33 + (j>>1)] = (unsigned int)f2bf(a) | ((unsigned int)f2bf(bb)<<16);
  }
  __syncthreads();
  #pragma unroll
  for (int it=0; it<8; it++){
    int u = it*256 + tid;
    int pxl = u >> 3, seg = u & 7;
    int pxg2 = c*256 + pxl;
    int y = pxg2 >> 5, x = pxg2 & 31;
    int pp = (y+1)*34 + (x+1);
    uint4 v;
    v.x = l[pxl*33 + seg*4 + 0];
    v.y = l[pxl*33 + seg*4 + 1];
    v.z = l[pxl*33 + seg*4 + 2];
    v.w = l[pxl*33 + seg*4 + 3];
    *(uint4*)(Ab + pp*64 + seg*8) = v;
  }
  // halo: 1056 units total, chunk c fills [c*264, c*264+264)
  uint4 z; z.x=0; z.y=0; z.z=0; z.w=0;
  for (int it=0; it<2; it++){
    int ul = it*256 + tid;
    if (ul >= 264) break;
    int u = c*264 + ul;
    int h = u >> 3, seg = u & 7;
    int pp;
    if (h < 34) pp = h;
    else if (h < 68) pp = 1122 + (h-34);
    else { int s = h-68; pp = (1 + (s>>1))*34 + (s&1)*33; }
    *(uint4*)(Ab + pp*64 + seg*8) = z;
  }
}

// ================= conv2 MFMA: out[n][128co][256px] = relu(At2 * Wt2 + b) =======================
__global__ __launch_bounds__(256) void k_c2mfma(const unsigned short* __restrict__ At,
    const unsigned short* __restrict__ Wt, const float* __restrict__ bias,
    float* __restrict__ out){
  int b = blockIdx.x;
  int wsw = (b & 7)*32 + (b >> 3);     // grid 256, 8 XCDs: image-halves co-located per XCD
  int half = wsw & 1;
  int n    = wsw >> 1;
  int tid = threadIdx.x;
  int wid = tid >> 6, lane = tid & 63;
  int wn = wid & 1, wm = wid >> 1;
  int lrow = lane & 15, lkb = lane >> 4;
  f32x4 acc[4][4];
  #pragma unroll
  for (int i=0;i<4;i++)
    #pragma unroll
    for (int j=0;j<4;j++){ acc[i][j].x=0.f; acc[i][j].y=0.f; acc[i][j].z=0.f; acc[i][j].w=0.f; }
  const unsigned short* Ab = At + (size_t)n*1156*64;
  int mbase = half*128 + wm*64;
  #pragma unroll
  for (int t=0; t<16; t++){
    int ky = t >> 2, kx = t & 3;
    #pragma unroll
    for (int kc=0; kc<2; kc++){
      int k0 = kc*32 + lkb*8;
      short8 a[4], b2[4];
      #pragma unroll
      for (int i=0;i<4;i++){
        int m = mbase + i*16 + lrow;
        int y = m >> 4, x = m & 15;
        int pp = (2*y+ky)*34 + (2*x+kx);
        a[i] = *(const short8*)(Ab + pp*64 + k0);
      }
      #pragma unroll
      for (int j=0;j<4;j++){
        int co = wn*64 + j*16 + lrow;
        b2[j] = *(const short8*)(Wt + (t*128 + co)*64 + k0);
      }
      #pragma unroll
      for (int i=0;i<4;i++)
        #pragma unroll
        for (int j=0;j<4;j++)
          acc[i][j] = __builtin_amdgcn_mfma_f32_16x16x32_bf16(a[i], b2[j], acc[i][j], 0,0,0);
    }
  }
  #pragma unroll
  for (int j=0;j<4;j++){
    int co = wn*64 + j*16 + lrow;
    float bv = bias[co];
    #pragma unroll
    for (int i=0;i<4;i++){
      int px0 = mbase + i*16 + lkb*4;
      f32x4 v = acc[i][j];
      v.x = relu_(v.x + bv); v.y = relu_(v.y + bv);
      v.z = relu_(v.z + bv); v.w = relu_(v.w + bv);
      *(f32x4*)(out + ((size_t)n*128+co)*256 + px0) = v;
    }
  }
}

// ================= conv3x3 weights: w[co][ci][t] f32 -> Wt[t][co][ci] bf16 ====================
__global__ __launch_bounds__(256) void k_wt(const float* __restrict__ w,
    unsigned short* __restrict__ Wt, int Co){
  int idx = blockIdx.x*256 + threadIdx.x;
  int tot = Co*128*9;
  if (idx >= tot) return;
  int ci = idx & 127;
  int r = idx >> 7;          // t*Co + co
  int t = r / Co, co = r - t*Co;
  Wt[idx] = f2bf(w[(co*128 + ci)*9 + t]);
}

// ================= deconv1 weights: w[ky][kx][ci][co] f32 (4,4,128,64) -> Wt1[t][co][ci] bf16 ====
__global__ __launch_bounds__(256) void k_wt1(const float* __restrict__ w,
    unsigned short* __restrict__ Wt){
  int idx = blockIdx.x*256 + threadIdx.x;   // 131072 total
  int ci = idx & 127;
  int r = idx >> 7;          // t*64 + co
  int t = r >> 6, co = r & 63;
  Wt[idx] = f2bf(w[t*8192 + ci*64 + co]);
}

// ================= conv3x3 act transpose: in[n][128][256] f32 -> At[n][324][128] bf16 ============
// grid 512 = 256 img x 2 y-halves; l[128*67] = 34.3 KB, 4 blocks/CU.
__global__ __launch_bounds__(256) void k_at(const float* __restrict__ in,
    unsigned short* __restrict__ At, int relu){
  __shared__ unsigned int l[128*67];     // [px_local][64 words(=128 ci)] pad 3 -> 67
  int b = blockIdx.x;
  int h = b & 1;            // y-half: px = h*128 + local
  int n = b >> 1;
  int tid = threadIdx.x;
  int pxl = tid & 127;      // local px
  int jh  = tid >> 7;       // word parity
  int pxg = h*128 + pxl;
  for (int w = jh; w < 64; w += 2){
    int j = w*2;
    float a = in[(n*128+j  )*256 + pxg];
    float bb = in[(n*128+j+1)*256 + pxg];
    if (relu){ a = relu_(a); bb = relu_(bb); }
    l[pxl*67 + w] = (unsigned int)f2bf(a) | ((unsigned int)f2bf(bb)<<16);
  }
  __syncthreads();
  unsigned short* Ab = At + (size_t)n*324*128;
  #pragma unroll
  for (int it=0; it<8; it++){
    int u = it*256 + tid;
    int px = u >> 4, seg = u & 15;     // px local 0..127
    int pxg2 = h*128 + px;
    int y = pxg2 >> 4, x = pxg2 & 15;
    int pp = (y+1)*18 + (x+1);
    uint4 v;
    v.x = l[px*67 + seg*4 + 0];
    v.y = l[px*67 + seg*4 + 1];
    v.z = l[px*67 + seg*4 + 2];
    v.w = l[px*67 + seg*4 + 3];
    *(uint4*)(Ab + pp*128 + seg*8) = v;
  }
  // halo: half h fills its boundary row (18 pp) + side cols of its 8 y-rows (16 pp) = 544 units
  uint4 z; z.x=0; z.y=0; z.z=0; z.w=0;
  for (int it=0; it<3; it++){
    int u = it*256 + tid;
    if (u >= 544) break;
    int hh = u >> 4, seg = u & 15;   // hh 0..33
    int pp;
    if (h == 0){
      if (hh < 18) pp = hh;                                      // top row 0
      else { int s = hh-18; pp = (1 + (s>>1))*18 + (s&1)*17; }   // rows 1..8 side cols
    } else {
      if (hh < 18) pp = 306 + hh;                                // bottom row 17
      else { int s = hh-18; pp = (9 + (s>>1))*18 + (s&1)*17; }   // rows 9..16 side cols
    }
    *(uint4*)(Ab + pp*128 + seg*8) = z;
  }
}

// ================= MFMA 3x3 conv with LDS-staged A panel ========================================
template<int CO>
__global__ __launch_bounds__(512) void k_c3mfma(const unsigned short* __restrict__ At,
    const unsigned short* __restrict__ Wt, const float* __restrict__ bias,
    float* __restrict__ out){
  constexpr int WNW = (CO==128) ? 2 : 1;   // waves along N
  constexpr int WMW = 8/WNW;               // waves along M
  constexpr int MT  = 16/WMW;              // m-tiles per wave
  constexpr int NT  = (CO/16)/WNW;         // n-tiles per wave
  __shared__ short8 lA[16][324];           // 82944 B
  int n = blockIdx.x;
  int tid = threadIdx.x;
  const short8* src = (const short8*)(At + (size_t)n*324*128);
  #pragma unroll
  for (int it=0; it<11; it++){
    int u = it*512 + tid;
    if (u < 5184) lA[u & 15][u >> 4] = src[u];
  }
  __syncthreads();
  int wid = tid >> 6, lane = tid & 63;
  int wn = wid % WNW, wm = wid / WNW;
  int lrow = lane & 15, lkb = lane >> 4;
  f32x4 acc[MT][NT];
  #pragma unroll
  for (int i=0;i<MT;i++)
    #pragma unroll
    for (int j=0;j<NT;j++){ acc[i][j].x=0.f; acc[i][j].y=0.f; acc[i][j].z=0.f; acc[i][j].w=0.f; }
  for (int t=0; t<9; t++){
    int ky = t/3, kx = t - 3*(t/3);
    #pragma unroll
    for (int kc=0; kc<4; kc++){
      int ch = kc*4 + lkb;
      int k0 = kc*32 + lkb*8;
      short8 a[MT], b[NT];
      #pragma unroll
      for (int i=0;i<MT;i++){
        int m = wm*(MT*16) + i*16 + lrow;
        int y = m >> 4, x = m & 15;
        int pp = (y+ky)*18 + (x+kx);
        a[i] = lA[ch][pp];
      }
      #pragma unroll
      for (int j=0;j<NT;j++){
        int co = wn*(NT*16) + j*16 + lrow;
        b[j] = *(const short8*)(Wt + (t*CO + co)*128 + k0);
      }
      #pragma unroll
      for (int i=0;i<MT;i++)
        #pragma unroll
        for (int j=0;j<NT;j++)
          acc[i][j] = __builtin_amdgcn_mfma_f32_16x16x32_bf16(a[i], b[j], acc[i][j], 0,0,0);
    }
  }
  #pragma unroll
  for (int j=0;j<NT;j++){
    int co = wn*(NT*16) + j*16 + lrow;
    float bv = bias[co];
    #pragma unroll
    for (int i=0;i<MT;i++){
      int px0 = wm*(MT*16) + i*16 + lkb*4;
      f32x4 v = acc[i][j];
      v.x += bv; v.y += bv; v.z += bv; v.w += bv;
      *(f32x4*)(out + ((size_t)n*CO+co)*256 + px0) = v;
    }
  }
}

// ================= deconv1 MFMA with LDS-staged panel: 2 parity classes per block ===============
__global__ __launch_bounds__(512) void k_dc1mfma(const unsigned short* __restrict__ At,
    const unsigned short* __restrict__ Wt, const float* __restrict__ bias,
    float* __restrict__ out){
  __shared__ short8 lA[16][324];           // 82944 B
  int b = blockIdx.x;
  int wsw = (b & 7)*64 + (b >> 3);         // grid 512, 8 XCDs: image-halves co-located
  int half = wsw & 1;
  int n    = wsw >> 1;
  int tid = threadIdx.x;
  const short8* src = (const short8*)(At + (size_t)n*324*128);
  #pragma unroll
  for (int it=0; it<11; it++){
    int u = it*512 + tid;
    if (u < 5184) lA[u & 15][u >> 4] = src[u];
  }
  __syncthreads();
  int wid = tid >> 6, lane = tid & 63;
  int cls = half*2 + (wid >> 2);
  int wm  = wid & 3;
  int p_y = cls >> 1, p_x = cls & 1;
  int lrow = lane & 15, lkb = lane >> 4;
  f32x4 acc[4][4];
  #pragma unroll
  for (int i=0;i<4;i++)
    #pragma unroll
    for (int j=0;j<4;j++){ acc[i][j].x=0.f; acc[i][j].y=0.f; acc[i][j].z=0.f; acc[i][j].w=0.f; }
  #pragma unroll
  for (int kc=0; kc<16; kc++){
    int tapi = kc >> 2;                 // a*2+b
    int a = tapi >> 1, bb = tapi & 1;
    int ch = (kc & 3)*4 + lkb;
    int k0 = (kc & 3)*32 + lkb*8;
    int t = (p_y + 2*a)*4 + (p_x + 2*bb);
    short8 av[4], bv[4];
    #pragma unroll
    for (int i=0;i<4;i++){
      int m = wm*64 + i*16 + lrow;
      int gy = m >> 4, gx = m & 15;
      int pp = (gy + p_y + a)*18 + (gx + p_x + bb);
      av[i] = lA[ch][pp];
    }
    #pragma unroll
    for (int j=0;j<4;j++){
      int co = j*16 + lrow;
      bv[j] = *(const short8*)(Wt + (t*64 + co)*128 + k0);
    }
    #pragma unroll
    for (int i=0;i<4;i++)
      #pragma unroll
      for (int j=0;j<4;j++)
        acc[i][j] = __builtin_amdgcn_mfma_f32_16x16x32_bf16(av[i], bv[j], acc[i][j], 0,0,0);
  }
  #pragma unroll
  for (int j=0;j<4;j++){
    int co = j*16 + lrow;
    float bvf = bias[co];
    float* op = out + (((size_t)n*64 + co)*4 + cls)*256;
    #pragma unroll
    for (int i=0;i<4;i++){
      int m0 = wm*64 + i*16 + lkb*4;
      f32x4 v = acc[i][j];
      v.x = relu_(v.x + bvf); v.y = relu_(v.y + bvf);
      v.z = relu_(v.z + bvf); v.w = relu_(v.w + bvf);
      *(f32x4*)(op + m0) = v;
    }
  }
}

// ================= residual 1x1: h += b + W2 @ relu(r);  co-half split, XCD co-located ==========
// grid 512 = 256 img x 2 co-halves; each block does 64 co.
__global__ __launch_bounds__(256) void k_res1x1(const float* __restrict__ r,
    const float* __restrict__ w, const float* __restrict__ bias, float* __restrict__ h){
  int b = blockIdx.x;
  int wsw = (b & 7)*64 + (b >> 3);
  int coh = wsw & 1;
  int n   = wsw >> 1;
  int tid = threadIdx.x;
  float rv[32];
  #pragma unroll
  for (int ci=0;ci<32;ci++) rv[ci] = relu_(r[(n*32+ci)*256 + tid]);
  int co0 = coh*64;
  for (int co=co0;co<co0+64;co++){
    float a = bias[co];
    const float* wp = w + co*32;
    #pragma unroll
    for (int ci=0;ci<32;ci++) a += rv[ci]*wp[ci];
    h[(n*128+co)*256 + tid] += a;
  }
}

// ================= generic f32 -> bf16 (optional relu), float4 granularity ======================
__global__ __launch_bounds__(256) void k_f2b(const float* __restrict__ in,
    unsigned short* __restrict__ out, int n4, int relu){
  int i = blockIdx.x*256 + threadIdx.x;
  if (i >= n4) return;
  float4 v = ((const float4*)in)[i];
  if (relu){ v.x=relu_(v.x); v.y=relu_(v.y); v.z=relu_(v.z); v.w=relu_(v.w); }
  uint2 o;
  o.x = (unsigned int)f2bf(v.x) | ((unsigned int)f2bf(v.y)<<16);
  o.y = (unsigned int)f2bf(v.z) | ((unsigned int)f2bf(v.w)<<16);
  ((uint2*)out)[i] = o;
}

// ================= decfc W transpose: w[256 k][32768 j] f32 -> Wt[j][256 k] bf16 ================
__global__ __launch_bounds__(256) void k_wtd(const float* __restrict__ w,
    unsigned short* __restrict__ Wt){
  __shared__ unsigned int l[256*65];     // [j][64 words(=128 k)+1]
  int j0 = blockIdx.x*256;               // grid 128
  int tid = threadIdx.x;
  for (int half=0; half<2; half++){
    __syncthreads();
    int kb = half*128;
    for (int k=0;k<128;k+=2){
      float a = w[(size_t)(kb+k  )*32768 + j0 + tid];
      float b = w[(size_t)(kb+k+1)*32768 + j0 + tid];
      l[tid*65 + (k>>1)] = (unsigned int)f2bf(a) | ((unsigned int)f2bf(b)<<16);
    }
    __syncthreads();
    #pragma unroll
    for (int it=0; it<16; it++){
      int u = it*256 + tid;
      int j = u >> 4, seg = u & 15;
      uint4 v;
      v.x = l[j*65 + seg*4 + 0];
      v.y = l[j*65 + seg*4 + 1];
      v.z = l[j*65 + seg*4 + 2];
      v.w = l[j*65 + seg*4 + 3];
      *(uint4*)(Wt + (size_t)(j0+j)*256 + kb + seg*8) = v;
    }
  }
}

// ================= encfc W transpose: w[32768 k][256 d] f32 -> Wt[(dbase+d)][32768 k] bf16 ======
__global__ __launch_bounds__(256) void k_wtfc(const float* __restrict__ w,
    unsigned short* __restrict__ Wt, int dbase){
  __shared__ unsigned int l[256*65];     // [d][64 words(=128 k)+1]
  int k0 = blockIdx.x*256;               // grid 128
  int tid = threadIdx.x;
  for (int half=0; half<2; half++){
    __syncthreads();
    int kb = half*128;
    for (int k=0;k<128;k+=2){
      float a = w[(size_t)(k0+kb+k  )*256 + tid];
      float b = w[(size_t)(k0+kb+k+1)*256 + tid];
      l[tid*65 + (k>>1)] = (unsigned int)f2bf(a) | ((unsigned int)f2bf(b)<<16);
    }
    __syncthreads();
    #pragma unroll
    for (int it=0; it<16; it++){
      int u = it*256 + tid;
      int d = u >> 4, seg = u & 15;
      uint4 v;
      v.x = l[d*65 + seg*4 + 0];
      v.y = l[d*65 + seg*4 + 1];
      v.z = l[d*65 + seg*4 + 2];
      v.w = l[d*65 + seg*4 + 3];
      *(uint4*)(Wt + (size_t)(dbase+d)*32768 + k0 + kb + seg*8) = v;
    }
  }
}

// ================= decfc MFMA: hd[m=256][j=32768] = zb * Wtd + b ================================
__global__ __launch_bounds__(512) void k_dfmfma(const unsigned short* __restrict__ zb,
    const unsigned short* __restrict__ Wt, const float* __restrict__ bias,
    float* __restrict__ hd){
  int jbase = blockIdx.x*128;
  int tid = threadIdx.x;
  int wid = tid >> 6, lane = tid & 63;
  int wn = wid & 1, wm = wid >> 1;
  int lrow = lane & 15, lkb = lane >> 4;
  f32x4 acc[4][4];
  #pragma unroll
  for (int i=0;i<4;i++)
    #pragma unroll
    for (int j=0;j<4;j++){ acc[i][j].x=0.f; acc[i][j].y=0.f; acc[i][j].z=0.f; acc[i][j].w=0.f; }
  #pragma unroll
  for (int kc=0; kc<8; kc++){
    int k0 = kc*32 + lkb*8;
    short8 a[4], b[4];
    #pragma unroll
    for (int i=0;i<4;i++){
      int m = wm*64 + i*16 + lrow;
      a[i] = *(const short8*)(zb + m*256 + k0);
    }
    #pragma unroll
    for (int j=0;j<4;j++){
      int jj = jbase + wn*64 + j*16 + lrow;
      b[j] = *(const short8*)(Wt + (size_t)jj*256 + k0);
    }
    #pragma unroll
    for (int i=0;i<4;i++)
      #pragma unroll
      for (int j=0;j<4;j++)
        acc[i][j] = __builtin_amdgcn_mfma_f32_16x16x32_bf16(a[i], b[j], acc[i][j], 0,0,0);
  }
  #pragma unroll
  for (int j=0;j<4;j++){
    int jj = jbase + wn*64 + j*16 + lrow;
    float bv = bias[jj];
    #pragma unroll
    for (int i=0;i<4;i++){
      int m0 = wm*64 + i*16 + lkb*4;
      f32x4 v = acc[i][j];
      hd[(size_t)(m0  )*32768 + jj] = v.x + bv;
      hd[(size_t)(m0+1)*32768 + jj] = v.y + bv;
      hd[(size_t)(m0+2)*32768 + jj] = v.z + bv;
      hd[(size_t)(m0+3)*32768 + jj] = v.w + bv;
    }
  }
}

// ================= encfc MFMA: P[ks][m=256][n=512] partials, K-split 64 x 512 ===================
__global__ __launch_bounds__(512) void k_efmfma(const unsigned short* __restrict__ Ab,
    const unsigned short* __restrict__ Wt, float* __restrict__ P){
  int ks = blockIdx.x >> 2;
  int ng = blockIdx.x & 3;
  int kchunk = ks*512;
  int tid = threadIdx.x;
  int wid = tid >> 6, lane = tid & 63;
  int wn = wid & 1, wm = wid >> 1;
  int lrow = lane & 15, lkb = lane >> 4;
  f32x4 acc[4][4];
  #pragma unroll
  for (int i=0;i<4;i++)
    #pragma unroll
    for (int j=0;j<4;j++){ acc[i][j].x=0.f; acc[i][j].y=0.f; acc[i][j].z=0.f; acc[i][j].w=0.f; }
  #pragma unroll
  for (int kc=0; kc<16; kc++){
    int k0 = kchunk + kc*32 + lkb*8;
    short8 a[4], b[4];
    #pragma unroll
    for (int i=0;i<4;i++){
      int m = wm*64 + i*16 + lrow;
      a[i] = *(const short8*)(Ab + (size_t)m*32768 + k0);
    }
    #pragma unroll
    for (int j=0;j<4;j++){
      int n = ng*128 + wn*64 + j*16 + lrow;
      b[j] = *(const short8*)(Wt + (size_t)n*32768 + k0);
    }
    #pragma unroll
    for (int i=0;i<4;i++)
      #pragma unroll
      for (int j=0;j<4;j++)
        acc[i][j] = __builtin_amdgcn_mfma_f32_16x16x32_bf16(a[i], b[j], acc[i][j], 0,0,0);
  }
  #pragma unroll
  for (int j=0;j<4;j++){
    int n = ng*128 + wn*64 + j*16 + lrow;
    #pragma unroll
    for (int i=0;i<4;i++){
      int m0 = wm*64 + i*16 + lkb*4;
      f32x4 v = acc[i][j];
      P[((size_t)ks*256 + m0  )*512 + n] = v.x;
      P[((size_t)ks*256 + m0+1)*512 + n] = v.y;
      P[((size_t)ks*256 + m0+2)*512 + n] = v.z;
      P[((size_t)ks*256 + m0+3)*512 + n] = v.w;
    }
  }
}

__global__ __launch_bounds__(256) void k_efred(const float* __restrict__ P,
    const float* __restrict__ bmu, const float* __restrict__ blv,
    float* __restrict__ mu, float* __restrict__ lv){
  int idx = blockIdx.x*256 + threadIdx.x;   // 65536
  int m = idx >> 8, d = idx & 255;
  float sm=0.f, sl=0.f;
  for (int ks=0; ks<64; ks++){
    size_t base = ((size_t)ks*256 + m)*512;
    sm += P[base + d];
    sl += P[base + 256 + d];
  }
  mu[idx] = sm + bmu[d];
  lv[idx] = sl + blv[d];
}

// ================= chain GCN helpers ==========================
__global__ void k_deg(const int* __restrict__ ei, int ne, float* __restrict__ deg,
                      float* __restrict__ dinv){
  int n = threadIdx.x;                       // 1 block x 256
  const int* dst = ei + ne;
  int c = 1;
  for (int e=0;e<ne;e++) c += (dst[e]==n) ? 1 : 0;
  deg[n]  = (float)c;
  dinv[n] = rsqrtf((float)c);
}

// gemm256 + zero agg fused (same grid covers both)
__global__ __launch_bounds__(256) void k_gemm256(const float* __restrict__ v,
    const float* __restrict__ w, float* __restrict__ xl, float* __restrict__ agg){
  __shared__ float vl[256];
  int n = blockIdx.x, tid = threadIdx.x;
  vl[tid] = v[(n<<8)+tid];
  agg[(n<<8)+tid] = 0.f;
  __syncthreads();
  float a=0.f;
  for (int k=0;k<256;k++) a += vl[k]*w[(k<<8)+tid];
  xl[(n<<8)+tid]=a;
}

__global__ __launch_bounds__(256) void k_edge(const int* __restrict__ ei, int ne,
    const float* __restrict__ xl, const float* __restrict__ dinv, float* __restrict__ agg){
  int e = blockIdx.x, d = threadIdx.x;
  int s = ei[e], t = ei[ne+e];
  float c = dinv[s]*dinv[t];
  atomicAdd(&agg[(t<<8)+d], xl[(s<<8)+d]*c);
}

__global__ __launch_bounds__(256) void k_gcnout(const float* __restrict__ agg,
    const float* __restrict__ xl, const float* __restrict__ deg, const float* __restrict__ bias,
    float* __restrict__ vout, float* __restrict__ vout2){
  int idx = blockIdx.x*256 + threadIdx.x;
  int n = idx>>8, d = idx&255;
  float o = relu_(agg[idx] + xl[idx]/deg[n] + bias[d]);
  vout[idx]=o;
  if (vout2) vout2[idx]=o;
}

// ================= dim GNN ==========================
__global__ __launch_bounds__(256) void k_y1(const float* __restrict__ emb,
    const float* __restrict__ w, float* __restrict__ y1){
  int idx = blockIdx.x*256+threadIdx.x;   // 16384
  int i = idx>>6, h = idx&63;
  float a=0.f;
  #pragma unroll
  for (int k=0;k<16;k++) a += emb[i*16+k]*w[k*64+h];
  y1[idx]=a;
}

__global__ __launch_bounds__(256) void k_mask(const float* __restrict__ L,
    float* __restrict__ mask, float* __restrict__ rowcnt){
  __shared__ float red[256];
  int i = blockIdx.x, j = threadIdx.x;
  float m = (i!=j && (L[(i<<8)+j] + L[(j<<8)+i] > 0.f)) ? 1.f : 0.f;
  mask[(i<<8)+j]=m;
  red[j]=m; __syncthreads();
  for (int s=128;s>0;s>>=1){ if(j<s) red[j]+=red[j+s]; __syncthreads(); }
  if (j==0) rowcnt[i]=red[0];
}

__global__ __launch_bounds__(256) void k_dimdeg(const float* __restrict__ rowcnt,
    float* __restrict__ ddinv, float* __restrict__ fbflag){
  __shared__ float red[256];
  int i = threadIdx.x;
  red[i]=rowcnt[i]; __syncthreads();
  for (int s=128;s>0;s>>=1){ if(i<s) red[i]+=red[i+s]; __syncthreads(); }
  float fb = (red[0] > 0.f) ? 0.f : 1.f;
  float degi = 1.f + (fb>0.5f ? 255.f : rowcnt[i]);
  ddinv[i] = rsqrtf(degi);
  if (i==0) fbflag[0]=fb;
}

__global__ __launch_bounds__(64) void k_xd(const float* __restrict__ mask,
    const float* __restrict__ ddinv, const float* __restrict__ y1,
    const float* __restrict__ b, const float* __restrict__ fbflag, float* __restrict__ xd){
  int i = blockIdx.x, h = threadIdx.x;   // 64 threads
  float fb = fbflag[0];
  float dii = ddinv[i];
  float a=0.f;
  for (int j=0;j<256;j++){
    float ah = (j==i) ? 1.f : (fb>0.5f ? 1.f : mask[(i<<8)+j]);
    a += ah*dii*ddinv[j]*y1[(j<<6)+h];
  }
  xd[(i<<6)+h] = relu_(a + b[h]);
}

__global__ __launch_bounds__(256) void k_imp(const float* __restrict__ xd,
    const float* __restrict__ w2, const float* __restrict__ b2,
    const float* __restrict__ mask, const float* __restrict__ ddinv,
    const float* __restrict__ fbflag, float* __restrict__ imp, float* __restrict__ imp_out){
  __shared__ float t[256];
  int i = threadIdx.x;                   // 1 block x 256
  float a=0.f;
  #pragma unroll
  for (int h=0;h<64;h++) a += xd[(i<<6)+h]*w2[h];
  t[i]=a; __syncthreads();
  float fb=fbflag[0]; float dii=ddinv[i];
  float s=0.f;
  for (int j=0;j<256;j++){
    float ah = (j==i) ? 1.f : (fb>0.5f ? 1.f : mask[(i<<8)+j]);
    s += ah*dii*ddinv[j]*t[j];
  }
  float r = s + b2[0];
  imp[i]=r; imp_out[i]=r;
}

// ================= reparameterize (fused: writes z f32 + z bf16) ==========================
__global__ __launch_bounds__(256) void k_reparam(const float* __restrict__ mu,
    const float* __restrict__ lv, const float* __restrict__ eps,
    const float* __restrict__ v2, const float* __restrict__ imp, float* __restrict__ z,
    unsigned short* __restrict__ zb){
  int idx = blockIdx.x*256+threadIdx.x;   // 65536
  int d = idx&255;
  float s = expf(0.5f*lv[idx]);
  float zv = mu[idx] + s*(eps[idx]*(v2[idx]*imp[d]));
  z[idx] = zv;
  zb[idx] = f2bf(zv);
}

// ================= deconv2 + fused SSE: parity-plane in -> recon + ssep[512] ====================
// Per-parity, tile[4][1024] (16 KB) + reg prefetch + XCD swizzle + SSE epilogue (round-29, 63.7us).
__global__ __launch_bounds__(512) void k_deconv2(const float* __restrict__ in,
    const float* __restrict__ w, const float* __restrict__ bias, float* __restrict__ out,
    const float* __restrict__ xin, float* __restrict__ ssep){
  __shared__ float tile[4096];
  __shared__ float red[512];
  int b = blockIdx.x;
  int wsw = (b & 7)*64 + (b >> 3);     // 8 XCDs: both parities of an image on one XCD
  int p_x = wsw & 1;
  int n   = wsw >> 1;
  int tid = threadIdx.x;
  int xi = tid & 31, yb = tid >> 5;    // yb 0..15
  int x = 2*xi + p_x;
  int ix0 = xi + p_x - 1, ix1 = xi + p_x;
  bool okx0 = (unsigned)ix0 < 32u, okx1 = (unsigned)ix1 < 32u;
  int r0 = 2*yb - 1;                   // row window r0..r0+3
  int su[8], scil[8];
  #pragma unroll
  for (int t=0;t<8;t++){
    int u = t*512 + tid;
    int px = u & 1023;
    int r = px >> 5, c = px & 31;
    su[t] = (((r&1)<<1)|(c&1))*256 + ((r>>1)<<4) + (c>>1);
    scil[t] = u >> 10;
  }
  float acc[4][3];
  #pragma unroll
  for (int r=0;r<4;r++)
    #pragma unroll
    for (int c=0;c<3;c++) acc[r][c]=0.f;
  const float* ip0 = in + (size_t)n*65536;
  float rg[8];
  #pragma unroll
  for (int t=0;t<8;t++) rg[t] = ip0[(size_t)scil[t]*1024 + su[t]];
  for (int c0=0; c0<64; c0+=4){
    __syncthreads();
    #pragma unroll
    for (int t=0;t<8;t++) tile[t*512 + tid] = rg[t];
    __syncthreads();
    if (c0+4 < 64){
      #pragma unroll
      for (int t=0;t<8;t++) rg[t] = ip0[(size_t)(c0+4+scil[t])*1024 + su[t]];
    }
    #pragma unroll
    for (int cil=0; cil<4; cil++){
      const float* tl = tile + cil*1024;
      float tv[4][2];
      #pragma unroll
      for (int rr=0; rr<4; rr++){
        int row = r0 + rr;
        bool okr = (unsigned)row < 32u;
        tv[rr][0] = (okr && okx0) ? tl[row*32+ix0] : 0.f;
        tv[rr][1] = (okr && okx1) ? tl[row*32+ix1] : 0.f;
      }
      const float* wp = w + (c0+cil)*3;
      #pragma unroll
      for (int r=0;r<4;r++){
        int py = r & 1;
        int rA = (r==0)?0:((r==3)?2:1);
        int rB = (r==0)?1:((r==3)?3:2);
        #pragma unroll
        for (int bb=0;bb<2;bb++){
          int kx = p_x + 2*bb;
          const float* w0 = wp + (py*4+kx)*192;        // ky = py
          const float* w1 = wp + ((py+2)*4+kx)*192;    // ky = py+2
          float vA = tv[rA][bb], vB = tv[rB][bb];
          #pragma unroll
          for (int c=0;c<3;c++){
            acc[r][c] += vA * w0[c];
            acc[r][c] += vB * w1[c];
          }
        }
      }
    }
  }
  float sse_l = 0.f;
  #pragma unroll
  for (int c=0;c<3;c++){
    float bv = bias[c];
    #pragma unroll
    for (int r=0;r<4;r++){
      int y = 4*yb + r;
      size_t oi = (((size_t)n*3+c)*64 + y)*64 + x;
      float v = acc[r][c] + bv;
      out[oi] = v;
      float d = v - xin[oi];
      sse_l += d*d;
    }
  }
  red[tid] = sse_l; __syncthreads();
  for (int s=256;s>0;s>>=1){ if(tid<s) red[tid]+=red[tid+s]; __syncthreads(); }
  if (tid==0) ssep[b] = red[0];
}

// ================= reductions ==========================
__global__ __launch_bounds__(256) void k_stats(const float* __restrict__ mu,
    const float* __restrict__ lv, const float* __restrict__ z,
    float* __restrict__ z2part, float* __restrict__ entpart, float* __restrict__ klflag){
  __shared__ float r1[256], r2[256], r3[256];
  int d = blockIdx.x, n = threadIdx.x;
  int idx = (n<<8) + d;
  float m = mu[idx], l = lv[idx], zz = z[idx];
  float s2e = expf(l) + 1e-8f;
  float leps = logf(s2e);
  r1[n] = zz*zz;
  r2[n] = 1.f + leps;
  r3[n] = -0.5f*(1.f + leps - m*m - s2e);
  __syncthreads();
  for (int s=128;s>0;s>>=1){
    if (n<s){ r1[n]+=r1[n+s]; r2[n]+=r2[n+s]; r3[n]+=r3[n+s]; }
    __syncthreads();
  }
  if (n==0){
    z2part[d]=r1[0]; entpart[d]=r2[0];
    klflag[d] = (r3[0]*(1.f/256.f) > 0.01f) ? 1.f : 0.f;
  }
}

__global__ __launch_bounds__(256) void k_final(const float* __restrict__ ssepart,
    const float* __restrict__ z2part, const float* __restrict__ entpart,
    const float* __restrict__ klflag, float* __restrict__ out){
  __shared__ float red[256];
  int tid = threadIdx.x;
  float s=0.f;
  for (int i=tid;i<512;i+=256) s += ssepart[i];
  red[tid]=s; __syncthreads();
  for (int st=128;st>0;st>>=1){ if(tid<st) red[tid]+=red[tid+st]; __syncthreads(); }
  float sse = red[0]; __syncthreads();
  red[tid]=z2part[tid]; __syncthreads();
  for (int st=128;st>0;st>>=1){ if(tid<st) red[tid]+=red[tid+st]; __syncthreads(); }
  float z2 = red[0]; __syncthreads();
  red[tid]=entpart[tid]; __syncthreads();
  for (int st=128;st>0;st>>=1){ if(tid<st) red[tid]+=red[tid+st]; __syncthreads(); }
  float ent = red[0]; __syncthreads();
  red[tid]=klflag[tid]; __syncthreads();
  for (int st=128;st>0;st>>=1){ if(tid<st) red[tid]+=red[tid+st]; __syncthreads(); }
  if (tid==0){
    float logpxz  = -sse;
    float prior   = -0.5f*(z2 + 65536.f*1.8378770664093453f);
    float entropy = 0.5f*ent;
    out[OUT_ELBO] = logpxz + prior + entropy;
    out[OUT_NACT] = red[0];
  }
}

// ======================================================================================
extern "C" void kernel_launch(void* const* d_in, const int* in_sizes, int n_in,
                              void* d_out, int out_size, void* d_ws, size_t ws_size,
                              hipStream_t stream){
  const float* x    = (const float*)d_in[0];
  const float* eps  = (const float*)d_in[1];
  const int*   ei   = (const int*)d_in[2];
  const float* c1w  = (const float*)d_in[3];
  const float* c1b  = (const float*)d_in[4];
  const float* c2w  = (const float*)d_in[5];
  const float* c2b  = (const float*)d_in[6];
  const float* c3w  = (const float*)d_in[7];
  const float* c3b  = (const float*)d_in[8];
  const float* erw1 = (const float*)d_in[9];
  const float* erb1 = (const float*)d_in[10];
  const float* erw2 = (const float*)d_in[11];
  const float* erb2 = (const float*)d_in[12];
  const float* fmw  = (const float*)d_in[13];
  const float* fmb  = (const float*)d_in[14];
  const float* flw  = (const float*)d_in[15];
  const float* flb  = (const float*)d_in[16];
  const float* dfw  = (const float*)d_in[17];
  const float* dfb  = (const float*)d_in[18];
  const float* drw1 = (const float*)d_in[19];
  const float* drb1 = (const float*)d_in[20];
  const float* drw2 = (const float*)d_in[21];
  const float* drb2 = (const float*)d_in[22];
  const float* t1w  = (const float*)d_in[23];
  const float* t1b  = (const float*)d_in[24];
  const float* t2w  = (const float*)d_in[25];
  const float* t2b  = (const float*)d_in[26];
  const float* iw   = (const float*)d_in[27];
  const float* ib   = (const float*)d_in[28];
  const float* Lg   = (const float*)d_in[29];
  const float* emb  = (const float*)d_in[30];
  const float* g1w  = (const float*)d_in[31];
  const float* g1b  = (const float*)d_in[32];
  const float* g2w  = (const float*)d_in[33];
  const float* g2b  = (const float*)d_in[34];
  float* out = (float*)d_out;
  float* ws  = (float*)d_ws;
  int ne = in_sizes[2] / 2;   // 510

  // workspace layout (floats); total ~34.1M floats (~137 MB)
  float* A  = ws;                    // 16777216: h1, later deconv1 output (parity planes)
  float* Bb = ws + 16777216;         //  8388608: h2; encfc Wtfc bf16; later hd (decoder)
  float* Cc = Bb + 8388608;          //  8388608: h3 (encoder); conv2/decfc/deconv1 scratch
  float* Rr = A;                     //  2097152: res temp (aliases A[0..2M))
  float* P  = A + 2097152;           //  8388608: encfc MFMA partials [64][256][512]
  unsigned short* At = (unsigned short*)(A + 10485760);   // conv3 act bf16 (A dead then)
  unsigned short* Ab = (unsigned short*)(A + 10485760);   // encfc act bf16 (same region, seq use)
  unsigned short* Wt = (unsigned short*)(A + 15794176);   // conv3 wt bf16
  unsigned short* At2 = (unsigned short*)Cc;              // conv2 act bf16 (Cc free then)
  unsigned short* Wt2 = (unsigned short*)(Cc + 5242880);  // conv2 wt bf16
  unsigned short* Wtd = (unsigned short*)Cc;              // decfc W bf16 (Cc free at decode)
  unsigned short* Atd = (unsigned short*)Cc;              // deconv1 act bf16 (after decfc)
  unsigned short* Wt1 = (unsigned short*)(Cc + 5308416);  // deconv1 wt bf16
  unsigned short* Wtfc = (unsigned short*)Bb;             // encfc W bf16 [512][32768]
  float* S  = Cc + 8388608;
  float* mu     = S; S += 65536;
  float* lv     = S; S += 65536;
  float* v1     = S; S += 65536;
  float* v2     = S; S += 65536;
  float* xl     = S; S += 65536;
  float* agg    = S; S += 65536;
  float* zz     = S; S += 65536;
  float* mask   = S; S += 65536;
  float* y1     = S; S += 16384;
  float* xd     = S; S += 16384;
  float* zbf    = S; S += 32768;     // z bf16 (65536 bf16)
  float* deg    = S; S += 256;
  float* dinvb  = S; S += 256;
  float* rowcnt = S; S += 256;
  float* ddinv  = S; S += 256;
  float* fbflag = S; S += 256;
  float* impv   = S; S += 256;
  float* ssep   = S; S += 1024;
  float* z2p    = S; S += 256;
  float* entp   = S; S += 256;
  float* klf    = S; S += 256;
  unsigned short* zb = (unsigned short*)zbf;

  // ---- encoder ----
  k_conv1<<<512,512,0,stream>>>(x, c1w, c1b, A);
  // conv2 via MFMA, two 128-image passes (At2 scratch lives in Cc, dead until conv3)
  k_wt2<<<512,256,0,stream>>>(c2w, Wt2);
  for (int pass=0; pass<2; pass++){
    size_t n0 = (size_t)pass*128;
    k_at2<<<512,256,0,stream>>>(A + n0*65536, At2);
    k_c2mfma<<<256,256,0,stream>>>(At2, Wt2, c2b, Bb + n0*32768);
  }
  // enc conv3 (Co=128) via MFMA (LDS-staged A)
  k_wt<<<576,256,0,stream>>>(c3w, Wt, 128);
  k_at<<<512,256,0,stream>>>(Bb, At, 0);
  k_c3mfma<128><<<256,512,0,stream>>>(At, Wt, c3b, Cc);
  // enc res layer 0
  k_wt<<<144,256,0,stream>>>(erw1, Wt, 32);
  k_at<<<512,256,0,stream>>>(Cc, At, 1);
  k_c3mfma<32><<<256,512,0,stream>>>(At, Wt, erb1, Rr);
  k_res1x1<<<512,256,0,stream>>>(Rr, erw2, erb2, Cc);
  // enc res layer 1
  k_wt<<<144,256,0,stream>>>(erw1+36864, Wt, 32);
  k_at<<<512,256,0,stream>>>(Cc, At, 1);
  k_c3mfma<32><<<256,512,0,stream>>>(At, Wt, erb1+32, Rr);
  k_res1x1<<<512,256,0,stream>>>(Rr, erw2+4096, erb2+128, Cc);
  // encfc via MFMA: Ab = relu(Cc) bf16; Wtfc = [Wmu|Wlv]^T bf16 (in Bb, dead now)
  k_f2b<<<8192,256,0,stream>>>(Cc, Ab, 2097152, 1);
  k_wtfc<<<128,256,0,stream>>>(fmw, Wtfc, 0);
  k_wtfc<<<128,256,0,stream>>>(flw, Wtfc, 256);
  k_efmfma<<<256,512,0,stream>>>(Ab, Wtfc, P);
  k_efred<<<256,256,0,stream>>>(P, fmb, flb, mu, lv);

  // ---- instance GCN (2 layers, chain graph) ----
  k_deg<<<1,256,0,stream>>>(ei, ne, deg, dinvb);
  k_gemm256<<<256,256,0,stream>>>(mu, iw, xl, agg);
  k_edge<<<ne,256,0,stream>>>(ei, ne, xl, dinvb, agg);
  k_gcnout<<<256,256,0,stream>>>(agg, xl, deg, ib, v1, nullptr);
  k_gemm256<<<256,256,0,stream>>>(v1, iw+65536, xl, agg);
  k_edge<<<ne,256,0,stream>>>(ei, ne, xl, dinvb, agg);
  k_gcnout<<<256,256,0,stream>>>(agg, xl, deg, ib+256, v2, out + OUT_VINST);

  // ---- dim GNN ----
  k_y1<<<64,256,0,stream>>>(emb, g1w, y1);
  k_mask<<<256,256,0,stream>>>(Lg, mask, rowcnt);
  k_dimdeg<<<1,256,0,stream>>>(rowcnt, ddinv, fbflag);
  k_xd<<<256,64,0,stream>>>(mask, ddinv, y1, g1b, fbflag, xd);
  k_imp<<<1,256,0,stream>>>(xd, g2w, g2b, mask, ddinv, fbflag, impv, out + OUT_IMP);

  // ---- reparameterize + decode ----
  k_reparam<<<256,256,0,stream>>>(mu, lv, eps, v2, impv, zz, zb);
  // decfc via MFMA: Wtd = W^T bf16 (Cc region, free now)
  k_wtd<<<128,256,0,stream>>>(dfw, Wtd);
  k_dfmfma<<<256,512,0,stream>>>(zb, Wtd, dfb, Bb);
  // dec res layer 0
  k_wt<<<144,256,0,stream>>>(drw1, Wt, 32);
  k_at<<<512,256,0,stream>>>(Bb, At, 1);
  k_c3mfma<32><<<256,512,0,stream>>>(At, Wt, drb1, Rr);
  k_res1x1<<<512,256,0,stream>>>(Rr, drw2, drb2, Bb);
  // dec res layer 1
  k_wt<<<144,256,0,stream>>>(drw1+36864, Wt, 32);
  k_at<<<512,256,0,stream>>>(Bb, At, 1);
  k_c3mfma<32><<<256,512,0,stream>>>(At, Wt, drb1+32, Rr);
  k_res1x1<<<512,256,0,stream>>>(Rr, drw2+4096, drb2+128, Bb);
  // deconv1 via MFMA (LDS-staged panel, 2 parity classes per block, XCD-swizzled)
  k_wt1<<<512,256,0,stream>>>(t1w, Wt1);
  k_at<<<512,256,0,stream>>>(Bb, Atd, 1);
  k_dc1mfma<<<512,512,0,stream>>>(Atd, Wt1, t1b, A);
  k_deconv2<<<512,512,0,stream>>>(A, t2w, t2b, out, x, ssep);

  // ---- losses / stats ----
  k_stats<<<256,256,0,stream>>>(mu, lv, zz, z2p, entp, klf);
  k_final<<<1,256,0,stream>>>(ssep, z2p, entp, klf, out);
}